// Round 14
// baseline (817.709 us; speedup 1.0000x reference)
//
#include <hip/hip_runtime.h>

// SLAYER SNN forward, round 14 = round 12 with:
//  - convs in round-10's proven 8-wave/512-thread z=1 shape (tile staged ONCE;
//    round-13 showed z-splits double staging without shrinking LDS) + round-12
//    float2 epilogue for even-HW.
//  - ppp prefetch deepened 4->8 (double rotation, static indices only).
// Everything else identical to round 12 (best known, 705us).
// All fp32; IIR op ordering bit-matches the reference scan.

#define TT 300

#define A1 0.9048374180359595f   // exp(-1/10)
#define C1 0.2718281828459045f   // e/10
#define A2 0.36787944117144233f  // exp(-1)
#define C2 2.718281828459045f    // e
#define KREF (20.0f * C2)
#define THETA_F 10.0f

typedef float v2f __attribute__((ext_vector_type(2)));

struct IIR {
  float p1, q1, p2, q2;
  __device__ IIR() : p1(0.f), q1(0.f), p2(0.f), q2(0.f) {}
  __device__ inline float step(float xin) {
    q1 = A1 * q1 + A1 * p1;
    float y = C1 * q1;
    p1 = A1 * p1 + xin;
    q2 = A2 * q2 + A2 * p2;
    float u = y - KREF * q2;
    float s = (u >= THETA_F) ? 1.0f : 0.0f;
    p2 = A2 * p2 + s;
    return s;
  }
};

// ---------------- generic tiled transpose: in[R][C] -> out[C][R] ----------------
__global__ __launch_bounds__(256) void transpose_rc(const float* __restrict__ in,
                                                    float* __restrict__ out,
                                                    int R, int C) {
  __shared__ float tile[64][65];
  int c0 = blockIdx.x * 64, r0 = blockIdx.y * 64;
  int tx = threadIdx.x & 63, ty = threadIdx.x >> 6;
  for (int i = ty; i < 64; i += 4) {
    int r = r0 + i, c = c0 + tx;
    if (r < R && c < C) tile[i][tx] = in[(long)r * C + c];
  }
  __syncthreads();
  for (int i = ty; i < 64; i += 4) {
    int c = c0 + i, r = r0 + tx;
    if (c < C && r < R) out[(long)c * R + r] = tile[tx][i];
  }
}

// ---------------- conv-weight transposes, one launch ----------------
__global__ __launch_bounds__(256) void prep_w(const float* __restrict__ Wc1,
                                              const float* __restrict__ Wc2,
                                              const float* __restrict__ Wc3,
                                              float* __restrict__ Wt1,
                                              float* __restrict__ Wt2,
                                              float* __restrict__ Wt3) {
  int i = blockIdx.x * 256 + threadIdx.x;
  if (i < 1200) { int co = i / 50, k = i % 50; Wt1[k * 24 + co] = Wc1[i]; return; }
  i -= 1200;
  if (i < 10368) { int co = i / 216, k = i % 216; Wt2[k * 48 + co] = Wc2[i]; return; }
  i -= 10368;
  if (i < 41472) { int co = i / 432, k = i % 432; Wt3[k * 96 + co] = Wc3[i]; }
}

// ---------------- per-timestep conv, time-major, 8 waves/block, tile staged once ----------------
// S: [T][B][CIN][HW][HW], Wt: [CIN][KS][KS][CO], U: [T][B][CO][HW][HW]
// 8 waves; wave w -> channels [w*NCO, +NCO); lane -> (y, x-group) slot.
template <int CIN, int HW, int KS, int PAD, int CO, int NCO, int NPX, int RS, int NITER>
__global__ __launch_bounds__(512, 4) void conv_tm9(const float* __restrict__ S,
                                                   const float* __restrict__ Wt,
                                                   float* __restrict__ U) {
  constexpr int PH = HW + 2 * PAD;
  constexpr int TILE = CIN * PH * RS;
  constexpr int XG = (HW + NPX - 1) / NPX;
  constexpr int SLOTS = HW * XG;
  constexpr int WIN = NPX + KS - 1;
  constexpr int NP2 = NPX / 2;
  __shared__ float lin[TILE + WIN];
  const int t = blockIdx.x, b = blockIdx.y, B = gridDim.y;

  for (int i = threadIdx.x; i < TILE + WIN; i += 512) lin[i] = 0.f;
  __syncthreads();
  const float* src = S + ((long)t * B + b) * (CIN * HW * HW);
  for (int i = threadIdx.x; i < CIN * HW * HW; i += 512) {
    int ci = i / (HW * HW), r = i % (HW * HW);
    int iy = r / HW, ix = r % HW;
    lin[ci * PH * RS + (iy + PAD) * RS + ix + PAD] = src[i];
  }
  __syncthreads();

  const int lane = threadIdx.x & 63;
  const int co0 = __builtin_amdgcn_readfirstlane(threadIdx.x >> 6) * NCO;
  const float* wb = Wt + co0;

  for (int it = 0; it < NITER; ++it) {
    int slot = lane + 64 * it;
    bool act = slot < SLOTS;
    int ss = act ? slot : 0;
    int y = ss / XG, x0 = (ss % XG) * NPX;
    const float* base = lin + y * RS + x0;
    v2f acc[NCO][NP2];
#pragma unroll
    for (int j = 0; j < NCO; ++j)
#pragma unroll
      for (int p = 0; p < NP2; ++p) acc[j][p] = (v2f)(0.f);

    for (int ci = 0; ci < CIN; ++ci) {
      const float* bp = base + ci * (PH * RS);
#pragma unroll
      for (int dy = 0; dy < KS; ++dy) {
        float win[WIN];
#pragma unroll
        for (int k = 0; k < WIN; ++k) win[k] = bp[dy * RS + k];
#pragma unroll
        for (int dx = 0; dx < KS; ++dx) {
          float wv[NCO];
#pragma unroll
          for (int j = 0; j < NCO; ++j)
            wv[j] = wb[(((ci * KS + dy) * KS + dx) * CO) + j];
#pragma unroll
          for (int p = 0; p < NP2; ++p) {
            v2f xp;
            xp.x = win[2 * p + dx];
            xp.y = win[2 * p + 1 + dx];
#pragma unroll
            for (int j = 0; j < NCO; ++j)
              acc[j][p] += xp * wv[j];
          }
        }
      }
    }
    if (act) {
      float* up = U + (((long)t * B + b) * CO + co0) * (HW * HW) + y * HW + x0;
#pragma unroll
      for (int j = 0; j < NCO; ++j)
#pragma unroll
        for (int p = 0; p < NP2; ++p) {
          if constexpr (HW % 2 == 0) {
            if (x0 + 2 * p + 1 < HW) {
              float2 st; st.x = acc[j][p].x; st.y = acc[j][p].y;
              *(float2*)(up + j * (HW * HW) + 2 * p) = st;
            }
          } else {
            if (x0 + 2 * p < HW) up[j * (HW * HW) + 2 * p] = acc[j][p].x;
            if (x0 + 2 * p + 1 < HW) up[j * (HW * HW) + 2 * p + 1] = acc[j][p].y;
          }
        }
    }
  }
}

// ---------------- fused psp->pool(x11)->psp, 4 lanes/neuron, 8-deep prefetch ----------------
// Double rotation: consume 4 per iter, prefetch 4 at distance 8. Static indices.
template <int C, int HIN, int HOUT>
__global__ __launch_bounds__(128) void ppp4_tm(const float* __restrict__ U,
                                               float* __restrict__ out, int B) {
  const int NOUT = B * C * HOUT * HOUT;
  const long SIN = (long)B * C * HIN * HIN;
  int id = blockIdx.x * 128 + threadIdx.x;
  int sub = id & 3, m = id >> 2;
  bool active = m < NOUT;
  int mm = active ? m : 0;
  int x2 = mm % HOUT;
  int y2 = (mm / HOUT) % HOUT;
  int c = (mm / (HOUT * HOUT)) % C;
  int b = mm / (C * HOUT * HOUT);
  int iy = 2 * y2 + (sub >> 1), ix = 2 * x2 + (sub & 1);
  bool valid = active && iy < HIN && ix < HIN;
  const float* base = U + ((long)(b * C + c) * HIN + iy) * HIN + ix;
  bool writer = active && (sub == 0);
  float* op = out + mm;
  IIR si, so;
  float p0 = valid ? base[0] : 0.f;
  float p1 = valid ? base[SIN] : 0.f;
  float p2 = valid ? base[2 * SIN] : 0.f;
  float p3 = valid ? base[3 * SIN] : 0.f;
  float p4 = valid ? base[4 * SIN] : 0.f;
  float p5 = valid ? base[5 * SIN] : 0.f;
  float p6 = valid ? base[6 * SIN] : 0.f;
  float p7 = valid ? base[7 * SIN] : 0.f;
  for (int tb = 0; tb < TT; tb += 4) {
    float a0 = p0, a1 = p1, a2 = p2, a3 = p3;
    p0 = p4; p1 = p5; p2 = p6; p3 = p7;
    // prefetch distance 8 (tb+8..tb+11); tail overreads land in allocated ws
    const float* nb = base + (long)(tb + 8) * SIN;
    p4 = valid ? nb[0] : 0.f;
    p5 = valid ? nb[SIN] : 0.f;
    p6 = valid ? nb[2 * SIN] : 0.f;
    p7 = valid ? nb[3 * SIN] : 0.f;
    {
      float s = si.step(a0);
      float v = s + __shfl_xor(s, 1); v += __shfl_xor(v, 2);
      float o = so.step(11.0f * v);
      if (writer) op[(long)tb * NOUT] = o;
    }
    {
      float s = si.step(a1);
      float v = s + __shfl_xor(s, 1); v += __shfl_xor(v, 2);
      float o = so.step(11.0f * v);
      if (writer) op[(long)(tb + 1) * NOUT] = o;
    }
    {
      float s = si.step(a2);
      float v = s + __shfl_xor(s, 1); v += __shfl_xor(v, 2);
      float o = so.step(11.0f * v);
      if (writer) op[(long)(tb + 2) * NOUT] = o;
    }
    {
      float s = si.step(a3);
      float v = s + __shfl_xor(s, 1); v += __shfl_xor(v, 2);
      float o = so.step(11.0f * v);
      if (writer) op[(long)(tb + 3) * NOUT] = o;
    }
  }
}

// ---------------- dense7k: split-k x8 GEMM, P[kz][row][o] partials ----------------
__global__ __launch_bounds__(256) void dense7k(const float* __restrict__ S,
                                               const float* __restrict__ Wt,
                                               float* __restrict__ P) {
  const int r0 = blockIdx.x * 16 + (threadIdx.x >> 6) * 4;
  const int kz = blockIdx.y;
  const int lane = threadIdx.x & 63;
  const float* s0 = S + (long)r0 * 2400;
  const float* s1 = s0 + 2400;
  const float* s2 = s0 + 4800;
  const float* s3 = s0 + 7200;
  const float* wp = Wt + lane * 4;
  v2f aA[4], aB[4];
#pragma unroll
  for (int o = 0; o < 4; ++o) { aA[o] = (v2f)(0.f); aB[o] = (v2f)(0.f); }
  const int k0 = kz * 300, k1 = k0 + 300;
  for (int k = k0; k < k1; k += 4) {
    float4 a0 = *(const float4*)(s0 + k);
    float4 a1 = *(const float4*)(s1 + k);
    float4 a2 = *(const float4*)(s2 + k);
    float4 a3 = *(const float4*)(s3 + k);
#define DSTEP(KK, AX)                                                        \
    {                                                                        \
      float4 w = *(const float4*)(wp + (long)(k + KK) * 256);                \
      v2f pA, pB;                                                            \
      pA.x = a0.AX; pA.y = a1.AX; pB.x = a2.AX; pB.y = a3.AX;                \
      aA[0] += pA * w.x; aA[1] += pA * w.y; aA[2] += pA * w.z; aA[3] += pA * w.w; \
      aB[0] += pB * w.x; aB[1] += pB * w.y; aB[2] += pB * w.z; aB[3] += pB * w.w; \
    }
    DSTEP(0, x) DSTEP(1, y) DSTEP(2, z) DSTEP(3, w)
#undef DSTEP
  }
  float* p = P + (long)kz * 307200 + (long)r0 * 256 + lane * 4;
#pragma unroll
  for (int o = 0; o < 4; ++o) p[o] = aA[o].x;
#pragma unroll
  for (int o = 0; o < 4; ++o) p[256 + o] = aA[o].y;
#pragma unroll
  for (int o = 0; o < 4; ++o) p[512 + o] = aB[o].x;
#pragma unroll
  for (int o = 0; o < 4; ++o) p[768 + o] = aB[o].y;
}

// ---------------- reduce8: U7 = sum of 8 partials (float4, ascending kz) ----------------
__global__ __launch_bounds__(256) void reduce8(const float* __restrict__ P,
                                               float* __restrict__ U7) {
  int i = blockIdx.x * 256 + threadIdx.x;  // over 76800 float4s
  if (i >= 76800) return;
  const float4* p = (const float4*)P;
  float4 a = p[i];
#pragma unroll
  for (int kz = 1; kz < 8; ++kz) {
    float4 b = p[(long)kz * 76800 + i];
    a.x += b.x; a.y += b.y; a.z += b.z; a.w += b.w;
  }
  ((float4*)U7)[i] = a;
}

// ---------------- psp7: psp+spike over U7, 4-deep prefetch ----------------
__global__ __launch_bounds__(128) void psp7(const float* __restrict__ U7,
                                            float* __restrict__ out) {
  int n = blockIdx.x * 128 + threadIdx.x;  // 0..1023
  IIR st;
  float pr0 = U7[n], pr1 = U7[1024 + n], pr2 = U7[2048 + n], pr3 = U7[3072 + n];
  for (int tb = 0; tb < TT; tb += 4) {
    float a0 = pr0, a1 = pr1, a2 = pr2, a3 = pr3;
    const float* nb = U7 + (long)(tb + 4) * 1024 + n;  // overreads into ws at end
    pr0 = nb[0]; pr1 = nb[1024]; pr2 = nb[2048]; pr3 = nb[3072];
    out[(long)tb * 1024 + n] = st.step(a0);
    out[(long)(tb + 1) * 1024 + n] = st.step(a1);
    out[(long)(tb + 2) * 1024 + n] = st.step(a2);
    out[(long)(tb + 3) * 1024 + n] = st.step(a3);
  }
}

// ---------------- dense8 ----------------
__global__ __launch_bounds__(256) void dense8(const float* __restrict__ S,
                                              const float* __restrict__ W,
                                              float* __restrict__ U) {
  int id = blockIdx.x * 256 + threadIdx.x;
  if (id >= 12000) return;
  int o = id % 10, row = id / 10;
  const float* sr = S + (long)row * 256;
  const float* wr = W + o * 256;
  float acc = 0.f;
  for (int k = 0; k < 256; k += 4) {
    float4 a = *(const float4*)(sr + k);
    float4 w = *(const float4*)(wr + k);
    acc += a.x * w.x; acc += a.y * w.y; acc += a.z * w.z; acc += a.w * w.w;
  }
  U[id] = acc;
}

// ---------------- final psp+spike + transpose to (B,10,T), prefetched ----------------
__global__ void psp8_out(const float* __restrict__ U, float* __restrict__ out) {
  int n = threadIdx.x;
  bool act = n < 40;
  int nn = act ? n : 0;
  IIR st;
  float pr0 = U[nn], pr1 = U[40 + nn], pr2 = U[80 + nn], pr3 = U[120 + nn];
  for (int tb = 0; tb < TT; tb += 4) {
    float a0 = pr0, a1 = pr1, a2 = pr2, a3 = pr3;
    const float* nb = U + (long)(tb + 4) * 40 + nn;  // overreads into ws at end
    pr0 = nb[0]; pr1 = nb[40]; pr2 = nb[80]; pr3 = nb[120];
    float o0 = st.step(a0), o1 = st.step(a1), o2 = st.step(a2), o3 = st.step(a3);
    if (act) {
      out[nn * TT + tb] = o0;
      out[nn * TT + tb + 1] = o1;
      out[nn * TT + tb + 2] = o2;
      out[nn * TT + tb + 3] = o3;
    }
  }
}

extern "C" void kernel_launch(void* const* d_in, const int* in_sizes, int n_in,
                              void* d_out, int out_size, void* d_ws, size_t ws_size,
                              hipStream_t stream) {
  const float* s_in = (const float*)d_in[0];
  const float* Wc1  = (const float*)d_in[1];
  const float* Wc2  = (const float*)d_in[2];
  const float* Wc3  = (const float*)d_in[3];
  const float* Wd4a = (const float*)d_in[4];
  const float* Wd4b = (const float*)d_in[5];

  float* Buf1 = (float*)d_ws;            // 33,292,800 floats (U1/U3/U5)
  float* Buf2 = Buf1 + 33292800;
  float* s2   = Buf2;                    //  8,323,200
  float* s4   = Buf2 + 8323200;          //  4,665,600
  float* Wt4a = Buf2 + 12988800;         //    614,400
  float* T0   = Buf2 + 13910400;         //  2,774,400
  float* Wt1  = Buf2 + 16684800;         //      1,200
  float* Wt2  = Buf2 + 16686000;         //     10,368
  float* Wt3  = Buf2 + 16696368;         //     41,472
  float* s7   = Buf2 + 16737840;         //    307,200
  float* P7   = Buf2 + 17045040;         //  2,457,600 (8 x 307,200 partials)
  float* U7   = Buf2 + 19502640;         //    307,200
  float* s6   = Buf2;                    //  2,880,000 (s2 region, dead by L6)
  float* U8   = Buf1;                    //     12,000 (Buf1 dead by L8)

  // prep: input -> time-major; Wd4a -> [k][o]; conv weights -> [k][co]
  transpose_rc<<<dim3(5, 145), 256, 0, stream>>>(s_in, T0, 9248, 300);
  transpose_rc<<<dim3(38, 4), 256, 0, stream>>>(Wd4a, Wt4a, 256, 2400);
  prep_w<<<208, 256, 0, stream>>>(Wc1, Wc2, Wc3, Wt1, Wt2, Wt3);

  // L1: conv 2->24 k5 p2 (8 waves x NCO=3, NPX=4, RS=39, NITER=5), tile staged once
  conv_tm9<2, 34, 5, 2, 24, 3, 4, 39, 5><<<dim3(300, 4), 512, 0, stream>>>(T0, Wt1, Buf1);
  // L1-psp + pool 34->17 + psp -> s2
  ppp4_tm<24, 34, 17><<<867, 128, 0, stream>>>(Buf1, s2, 4);
  // L3: conv 24->48 k3 p1 (8 waves x NCO=6, NPX=6, RS=19, NITER=1)
  conv_tm9<24, 17, 3, 1, 48, 6, 6, 19, 1><<<dim3(300, 4), 512, 0, stream>>>(s2, Wt2, Buf1);
  // L3-psp + pool 17->9 + psp -> s4
  ppp4_tm<48, 17, 9><<<486, 128, 0, stream>>>(Buf1, s4, 4);
  // L5: conv 48->96 k3 p1 (8 waves x NCO=12, NPX=2, RS=13, NITER=1)
  conv_tm9<48, 9, 3, 1, 96, 12, 2, 13, 1><<<dim3(300, 4), 512, 0, stream>>>(s4, Wt3, Buf1);
  // L5-psp + pool 9->5 + psp -> s6
  ppp4_tm<96, 9, 5><<<300, 128, 0, stream>>>(Buf1, s6, 4);
  // L7: dense 2400->256 split-k x8 ; fold partials ; psp -> s7
  dense7k<<<dim3(75, 8), 256, 0, stream>>>(s6, Wt4a, P7);
  reduce8<<<300, 256, 0, stream>>>(P7, U7);
  psp7<<<8, 128, 0, stream>>>(U7, s7);
  // L8: dense 256->10 ; psp + output transpose
  dense8<<<47, 256, 0, stream>>>(s7, Wd4b, U8);
  psp8_out<<<1, 64, 0, stream>>>(U8, (float*)d_out);
}

// Round 15
// 696.842 us; speedup vs baseline: 1.1734x; 1.1734x over previous
//
#include <hip/hip_runtime.h>

// SLAYER SNN forward, round 15 = round 12 with the float2 conv epilogue REMOVED.
// Round-14 profiling exposed it: the float2-pair store pattern (only ever active
// on L1, the sole even-HW conv) caused ~4x HBM write amplification (518MB vs
// 133MB logical) + full U1 read-back. Round-11's scalar guarded stores showed
// clean 132MB traffic. Everything else identical to round 12 (best clean
// config): L1/L3/L5 4-wave z=2 conv blocks, 4-deep ppp prefetch, split-k x8
// dense7 + reduce8 + psp7.
// All fp32; IIR op ordering bit-matches the reference scan.

#define TT 300

#define A1 0.9048374180359595f   // exp(-1/10)
#define C1 0.2718281828459045f   // e/10
#define A2 0.36787944117144233f  // exp(-1)
#define C2 2.718281828459045f    // e
#define KREF (20.0f * C2)
#define THETA_F 10.0f

typedef float v2f __attribute__((ext_vector_type(2)));

struct IIR {
  float p1, q1, p2, q2;
  __device__ IIR() : p1(0.f), q1(0.f), p2(0.f), q2(0.f) {}
  __device__ inline float step(float xin) {
    q1 = A1 * q1 + A1 * p1;
    float y = C1 * q1;
    p1 = A1 * p1 + xin;
    q2 = A2 * q2 + A2 * p2;
    float u = y - KREF * q2;
    float s = (u >= THETA_F) ? 1.0f : 0.0f;
    p2 = A2 * p2 + s;
    return s;
  }
};

// ---------------- generic tiled transpose: in[R][C] -> out[C][R] ----------------
__global__ __launch_bounds__(256) void transpose_rc(const float* __restrict__ in,
                                                    float* __restrict__ out,
                                                    int R, int C) {
  __shared__ float tile[64][65];
  int c0 = blockIdx.x * 64, r0 = blockIdx.y * 64;
  int tx = threadIdx.x & 63, ty = threadIdx.x >> 6;
  for (int i = ty; i < 64; i += 4) {
    int r = r0 + i, c = c0 + tx;
    if (r < R && c < C) tile[i][tx] = in[(long)r * C + c];
  }
  __syncthreads();
  for (int i = ty; i < 64; i += 4) {
    int c = c0 + i, r = r0 + tx;
    if (c < C && r < R) out[(long)c * R + r] = tile[tx][i];
  }
}

// ---------------- conv-weight transposes, one launch ----------------
__global__ __launch_bounds__(256) void prep_w(const float* __restrict__ Wc1,
                                              const float* __restrict__ Wc2,
                                              const float* __restrict__ Wc3,
                                              float* __restrict__ Wt1,
                                              float* __restrict__ Wt2,
                                              float* __restrict__ Wt3) {
  int i = blockIdx.x * 256 + threadIdx.x;
  if (i < 1200) { int co = i / 50, k = i % 50; Wt1[k * 24 + co] = Wc1[i]; return; }
  i -= 1200;
  if (i < 10368) { int co = i / 216, k = i % 216; Wt2[k * 48 + co] = Wc2[i]; return; }
  i -= 10368;
  if (i < 41472) { int co = i / 432, k = i % 432; Wt3[k * 96 + co] = Wc3[i]; }
}

// ---------------- per-timestep conv, time-major, 4 waves/block, z channel groups ----------------
// S: [T][B][CIN][HW][HW], Wt: [CIN][KS][KS][CO], U: [T][B][CO][HW][HW]
// Scalar guarded stores ONLY (float2-pair stores caused 4x HBM write
// amplification on L1 -- round 14 counters).
template <int CIN, int HW, int KS, int PAD, int CO, int NCO, int NPX, int RS, int NITER>
__global__ __launch_bounds__(256) void conv_tm8(const float* __restrict__ S,
                                                const float* __restrict__ Wt,
                                                float* __restrict__ U) {
  constexpr int PH = HW + 2 * PAD;
  constexpr int TILE = CIN * PH * RS;
  constexpr int XG = (HW + NPX - 1) / NPX;
  constexpr int SLOTS = HW * XG;
  constexpr int WIN = NPX + KS - 1;
  constexpr int NP2 = NPX / 2;
  __shared__ float lin[TILE + WIN];
  const int t = blockIdx.x, b = blockIdx.y, B = gridDim.y;

  for (int i = threadIdx.x; i < TILE + WIN; i += 256) lin[i] = 0.f;
  __syncthreads();
  const float* src = S + ((long)t * B + b) * (CIN * HW * HW);
  for (int i = threadIdx.x; i < CIN * HW * HW; i += 256) {
    int ci = i / (HW * HW), r = i % (HW * HW);
    int iy = r / HW, ix = r % HW;
    lin[ci * PH * RS + (iy + PAD) * RS + ix + PAD] = src[i];
  }
  __syncthreads();

  const int lane = threadIdx.x & 63;
  const int co0 = blockIdx.z * (4 * NCO) +
                  __builtin_amdgcn_readfirstlane(threadIdx.x >> 6) * NCO;
  const float* wb = Wt + co0;

  for (int it = 0; it < NITER; ++it) {
    int slot = lane + 64 * it;
    bool act = slot < SLOTS;
    int ss = act ? slot : 0;
    int y = ss / XG, x0 = (ss % XG) * NPX;
    const float* base = lin + y * RS + x0;
    v2f acc[NCO][NP2];
#pragma unroll
    for (int j = 0; j < NCO; ++j)
#pragma unroll
      for (int p = 0; p < NP2; ++p) acc[j][p] = (v2f)(0.f);

    for (int ci = 0; ci < CIN; ++ci) {
      const float* bp = base + ci * (PH * RS);
#pragma unroll
      for (int dy = 0; dy < KS; ++dy) {
        float win[WIN];
#pragma unroll
        for (int k = 0; k < WIN; ++k) win[k] = bp[dy * RS + k];
#pragma unroll
        for (int dx = 0; dx < KS; ++dx) {
          float wv[NCO];
#pragma unroll
          for (int j = 0; j < NCO; ++j)
            wv[j] = wb[(((ci * KS + dy) * KS + dx) * CO) + j];
#pragma unroll
          for (int p = 0; p < NP2; ++p) {
            v2f xp;
            xp.x = win[2 * p + dx];
            xp.y = win[2 * p + 1 + dx];
#pragma unroll
            for (int j = 0; j < NCO; ++j)
              acc[j][p] += xp * wv[j];
          }
        }
      }
    }
    if (act) {
      float* up = U + (((long)t * B + b) * CO + co0) * (HW * HW) + y * HW + x0;
#pragma unroll
      for (int j = 0; j < NCO; ++j)
#pragma unroll
        for (int p = 0; p < NP2; ++p) {
          if (x0 + 2 * p < HW) up[j * (HW * HW) + 2 * p] = acc[j][p].x;
          if (x0 + 2 * p + 1 < HW) up[j * (HW * HW) + 2 * p + 1] = acc[j][p].y;
        }
    }
  }
}

// ---------------- fused psp->pool(x11)->psp, 4 lanes/neuron, 4-deep prefetch ----------------
template <int C, int HIN, int HOUT>
__global__ __launch_bounds__(128) void ppp4_tm(const float* __restrict__ U,
                                               float* __restrict__ out, int B) {
  const int NOUT = B * C * HOUT * HOUT;
  const long SIN = (long)B * C * HIN * HIN;
  int id = blockIdx.x * 128 + threadIdx.x;
  int sub = id & 3, m = id >> 2;
  bool active = m < NOUT;
  int mm = active ? m : 0;
  int x2 = mm % HOUT;
  int y2 = (mm / HOUT) % HOUT;
  int c = (mm / (HOUT * HOUT)) % C;
  int b = mm / (C * HOUT * HOUT);
  int iy = 2 * y2 + (sub >> 1), ix = 2 * x2 + (sub & 1);
  bool valid = active && iy < HIN && ix < HIN;
  const float* base = U + ((long)(b * C + c) * HIN + iy) * HIN + ix;
  bool writer = active && (sub == 0);
  float* op = out + mm;
  IIR si, so;
  float pr0 = valid ? base[0] : 0.f;
  float pr1 = valid ? base[SIN] : 0.f;
  float pr2 = valid ? base[2 * SIN] : 0.f;
  float pr3 = valid ? base[3 * SIN] : 0.f;
  for (int tb = 0; tb < TT; tb += 4) {
    float a0 = pr0, a1 = pr1, a2 = pr2, a3 = pr3;
    const float* nb = base + (long)(tb + 4) * SIN;  // last iter overreads into ws
    pr0 = valid ? nb[0] : 0.f;
    pr1 = valid ? nb[SIN] : 0.f;
    pr2 = valid ? nb[2 * SIN] : 0.f;
    pr3 = valid ? nb[3 * SIN] : 0.f;
    {
      float s = si.step(a0);
      float v = s + __shfl_xor(s, 1); v += __shfl_xor(v, 2);
      float o = so.step(11.0f * v);
      if (writer) op[(long)tb * NOUT] = o;
    }
    {
      float s = si.step(a1);
      float v = s + __shfl_xor(s, 1); v += __shfl_xor(v, 2);
      float o = so.step(11.0f * v);
      if (writer) op[(long)(tb + 1) * NOUT] = o;
    }
    {
      float s = si.step(a2);
      float v = s + __shfl_xor(s, 1); v += __shfl_xor(v, 2);
      float o = so.step(11.0f * v);
      if (writer) op[(long)(tb + 2) * NOUT] = o;
    }
    {
      float s = si.step(a3);
      float v = s + __shfl_xor(s, 1); v += __shfl_xor(v, 2);
      float o = so.step(11.0f * v);
      if (writer) op[(long)(tb + 3) * NOUT] = o;
    }
  }
}

// ---------------- dense7k: split-k x8 GEMM, P[kz][row][o] partials ----------------
__global__ __launch_bounds__(256) void dense7k(const float* __restrict__ S,
                                               const float* __restrict__ Wt,
                                               float* __restrict__ P) {
  const int r0 = blockIdx.x * 16 + (threadIdx.x >> 6) * 4;
  const int kz = blockIdx.y;
  const int lane = threadIdx.x & 63;
  const float* s0 = S + (long)r0 * 2400;
  const float* s1 = s0 + 2400;
  const float* s2 = s0 + 4800;
  const float* s3 = s0 + 7200;
  const float* wp = Wt + lane * 4;
  v2f aA[4], aB[4];
#pragma unroll
  for (int o = 0; o < 4; ++o) { aA[o] = (v2f)(0.f); aB[o] = (v2f)(0.f); }
  const int k0 = kz * 300, k1 = k0 + 300;
  for (int k = k0; k < k1; k += 4) {
    float4 a0 = *(const float4*)(s0 + k);
    float4 a1 = *(const float4*)(s1 + k);
    float4 a2 = *(const float4*)(s2 + k);
    float4 a3 = *(const float4*)(s3 + k);
#define DSTEP(KK, AX)                                                        \
    {                                                                        \
      float4 w = *(const float4*)(wp + (long)(k + KK) * 256);                \
      v2f pA, pB;                                                            \
      pA.x = a0.AX; pA.y = a1.AX; pB.x = a2.AX; pB.y = a3.AX;                \
      aA[0] += pA * w.x; aA[1] += pA * w.y; aA[2] += pA * w.z; aA[3] += pA * w.w; \
      aB[0] += pB * w.x; aB[1] += pB * w.y; aB[2] += pB * w.z; aB[3] += pB * w.w; \
    }
    DSTEP(0, x) DSTEP(1, y) DSTEP(2, z) DSTEP(3, w)
#undef DSTEP
  }
  float* p = P + (long)kz * 307200 + (long)r0 * 256 + lane * 4;
#pragma unroll
  for (int o = 0; o < 4; ++o) p[o] = aA[o].x;
#pragma unroll
  for (int o = 0; o < 4; ++o) p[256 + o] = aA[o].y;
#pragma unroll
  for (int o = 0; o < 4; ++o) p[512 + o] = aB[o].x;
#pragma unroll
  for (int o = 0; o < 4; ++o) p[768 + o] = aB[o].y;
}

// ---------------- reduce8: U7 = sum of 8 partials (float4, ascending kz) ----------------
__global__ __launch_bounds__(256) void reduce8(const float* __restrict__ P,
                                               float* __restrict__ U7) {
  int i = blockIdx.x * 256 + threadIdx.x;  // over 76800 float4s
  if (i >= 76800) return;
  const float4* p = (const float4*)P;
  float4 a = p[i];
#pragma unroll
  for (int kz = 1; kz < 8; ++kz) {
    float4 b = p[(long)kz * 76800 + i];
    a.x += b.x; a.y += b.y; a.z += b.z; a.w += b.w;
  }
  ((float4*)U7)[i] = a;
}

// ---------------- psp7: psp+spike over U7, 4-deep prefetch ----------------
__global__ __launch_bounds__(128) void psp7(const float* __restrict__ U7,
                                            float* __restrict__ out) {
  int n = blockIdx.x * 128 + threadIdx.x;  // 0..1023
  IIR st;
  float pr0 = U7[n], pr1 = U7[1024 + n], pr2 = U7[2048 + n], pr3 = U7[3072 + n];
  for (int tb = 0; tb < TT; tb += 4) {
    float a0 = pr0, a1 = pr1, a2 = pr2, a3 = pr3;
    const float* nb = U7 + (long)(tb + 4) * 1024 + n;  // overreads into ws at end
    pr0 = nb[0]; pr1 = nb[1024]; pr2 = nb[2048]; pr3 = nb[3072];
    out[(long)tb * 1024 + n] = st.step(a0);
    out[(long)(tb + 1) * 1024 + n] = st.step(a1);
    out[(long)(tb + 2) * 1024 + n] = st.step(a2);
    out[(long)(tb + 3) * 1024 + n] = st.step(a3);
  }
}

// ---------------- dense8 ----------------
__global__ __launch_bounds__(256) void dense8(const float* __restrict__ S,
                                              const float* __restrict__ W,
                                              float* __restrict__ U) {
  int id = blockIdx.x * 256 + threadIdx.x;
  if (id >= 12000) return;
  int o = id % 10, row = id / 10;
  const float* sr = S + (long)row * 256;
  const float* wr = W + o * 256;
  float acc = 0.f;
  for (int k = 0; k < 256; k += 4) {
    float4 a = *(const float4*)(sr + k);
    float4 w = *(const float4*)(wr + k);
    acc += a.x * w.x; acc += a.y * w.y; acc += a.z * w.z; acc += a.w * w.w;
  }
  U[id] = acc;
}

// ---------------- final psp+spike + transpose to (B,10,T), prefetched ----------------
__global__ void psp8_out(const float* __restrict__ U, float* __restrict__ out) {
  int n = threadIdx.x;
  bool act = n < 40;
  int nn = act ? n : 0;
  IIR st;
  float pr0 = U[nn], pr1 = U[40 + nn], pr2 = U[80 + nn], pr3 = U[120 + nn];
  for (int tb = 0; tb < TT; tb += 4) {
    float a0 = pr0, a1 = pr1, a2 = pr2, a3 = pr3;
    const float* nb = U + (long)(tb + 4) * 40 + nn;  // overreads into ws at end
    pr0 = nb[0]; pr1 = nb[40]; pr2 = nb[80]; pr3 = nb[120];
    float o0 = st.step(a0), o1 = st.step(a1), o2 = st.step(a2), o3 = st.step(a3);
    if (act) {
      out[nn * TT + tb] = o0;
      out[nn * TT + tb + 1] = o1;
      out[nn * TT + tb + 2] = o2;
      out[nn * TT + tb + 3] = o3;
    }
  }
}

extern "C" void kernel_launch(void* const* d_in, const int* in_sizes, int n_in,
                              void* d_out, int out_size, void* d_ws, size_t ws_size,
                              hipStream_t stream) {
  const float* s_in = (const float*)d_in[0];
  const float* Wc1  = (const float*)d_in[1];
  const float* Wc2  = (const float*)d_in[2];
  const float* Wc3  = (const float*)d_in[3];
  const float* Wd4a = (const float*)d_in[4];
  const float* Wd4b = (const float*)d_in[5];

  float* Buf1 = (float*)d_ws;            // 33,292,800 floats (U1/U3/U5)
  float* Buf2 = Buf1 + 33292800;
  float* s2   = Buf2;                    //  8,323,200
  float* s4   = Buf2 + 8323200;          //  4,665,600
  float* Wt4a = Buf2 + 12988800;         //    614,400
  float* T0   = Buf2 + 13910400;         //  2,774,400
  float* Wt1  = Buf2 + 16684800;         //      1,200
  float* Wt2  = Buf2 + 16686000;         //     10,368
  float* Wt3  = Buf2 + 16696368;         //     41,472
  float* s7   = Buf2 + 16737840;         //    307,200
  float* P7   = Buf2 + 17045040;         //  2,457,600 (8 x 307,200 partials)
  float* U7   = Buf2 + 19502640;         //    307,200
  float* s6   = Buf2;                    //  2,880,000 (s2 region, dead by L6)
  float* U8   = Buf1;                    //     12,000 (Buf1 dead by L8)

  // prep: input -> time-major; Wd4a -> [k][o]; conv weights -> [k][co]
  transpose_rc<<<dim3(5, 145), 256, 0, stream>>>(s_in, T0, 9248, 300);
  transpose_rc<<<dim3(38, 4), 256, 0, stream>>>(Wd4a, Wt4a, 256, 2400);
  prep_w<<<208, 256, 0, stream>>>(Wc1, Wc2, Wc3, Wt1, Wt2, Wt3);

  // L1: conv 2->24 k5 p2 (4 waves x NCO=3, z=2, NPX=4, RS=39, NITER=5) -> 2400 blocks
  conv_tm8<2, 34, 5, 2, 24, 3, 4, 39, 5><<<dim3(300, 4, 2), 256, 0, stream>>>(T0, Wt1, Buf1);
  // L1-psp + pool 34->17 + psp -> s2
  ppp4_tm<24, 34, 17><<<867, 128, 0, stream>>>(Buf1, s2, 4);
  // L3: conv 24->48 k3 p1 (4 waves x NCO=6, z=2, NPX=6, RS=19, NITER=1) -> 2400 blocks
  conv_tm8<24, 17, 3, 1, 48, 6, 6, 19, 1><<<dim3(300, 4, 2), 256, 0, stream>>>(s2, Wt2, Buf1);
  // L3-psp + pool 17->9 + psp -> s4
  ppp4_tm<48, 17, 9><<<486, 128, 0, stream>>>(Buf1, s4, 4);
  // L5: conv 48->96 k3 p1 (4 waves x NCO=12, z=2, NPX=2, RS=13, NITER=1) -> 2400 blocks
  conv_tm8<48, 9, 3, 1, 96, 12, 2, 13, 1><<<dim3(300, 4, 2), 256, 0, stream>>>(s4, Wt3, Buf1);
  // L5-psp + pool 9->5 + psp -> s6
  ppp4_tm<96, 9, 5><<<300, 128, 0, stream>>>(Buf1, s6, 4);
  // L7: dense 2400->256 split-k x8 ; fold partials ; psp -> s7
  dense7k<<<dim3(75, 8), 256, 0, stream>>>(s6, Wt4a, P7);
  reduce8<<<300, 256, 0, stream>>>(P7, U7);
  psp7<<<8, 128, 0, stream>>>(U7, s7);
  // L8: dense 256->10 ; psp + output transpose
  dense8<<<47, 256, 0, stream>>>(s7, Wd4b, U8);
  psp8_out<<<1, 64, 0, stream>>>(U8, (float*)d_out);
}